// Round 6
// baseline (184.526 us; speedup 1.0000x reference)
//
#include <hip/hip_runtime.h>
#include <hip/hip_bf16.h>

using u16 = unsigned short;

static constexpr int N  = 2;
static constexpr int C  = 64;
static constexpr int H  = 256;
static constexpr int W  = 256;
static constexpr int Hd = 128;
static constexpr int Wd = 128;
static constexpr int Cm = 64;
static constexpr int KK = 25;
static constexpr int C2 = 256;
static constexpr int OC = 64;
static constexpr int HWP  = H * W;    // 65536
static constexpr int HDWD = Hd * Wd;  // 16384

__device__ __forceinline__ float bff(u16 u) {
    return __uint_as_float(((unsigned)u) << 16);
}
__device__ __forceinline__ float bflo(unsigned u) { return __uint_as_float(u << 16); }
__device__ __forceinline__ float bfhi(unsigned u) { return __uint_as_float(u & 0xffff0000u); }
__device__ __forceinline__ unsigned pack2(float a, float b) {
    __hip_bfloat16 ha = __float2bfloat16(a), hb = __float2bfloat16(b);
    union { __hip_bfloat16 h; u16 u; } ua{ha}, ub{hb};
    return (unsigned)ua.u | ((unsigned)ub.u << 16);
}

// ---------------- Kernel A: 1x1 down conv -> k1 PIXEL-MAJOR [n][px][cm] -----
__global__ __launch_bounds__(256) void kA_down(const float* __restrict__ x,
                                               const float* __restrict__ w,
                                               const float* __restrict__ b,
                                               u16* __restrict__ k1) {
    __shared__ u16   xt[64][256];    // bf16 x tile [c][px_local]   32 KB
    __shared__ float wt[64][66];     // w transposed [c][cm]
    const int tid = threadIdx.x;
    const int pg0 = blockIdx.x * 256;
    const int n   = pg0 >> 16;
    const int px0 = pg0 & (HWP - 1);

#pragma unroll
    for (int i = 0; i < 16; ++i) {
        int e  = i * 256 + tid;
        int cm = e >> 6, c = e & 63;
        wt[c][cm] = w[e];
    }
    const float* xb = x + (size_t)n * C * HWP + px0;
#pragma unroll
    for (int i = 0; i < 16; ++i) {
        int flat = i * 256 + tid;
        int row  = flat >> 6;
        int col4 = flat & 63;
        float4 v = *(const float4*)(xb + (size_t)row * HWP + col4 * 4);
        uint2 p;
        p.x = pack2(v.x, v.y);
        p.y = pack2(v.z, v.w);
        *(uint2*)&xt[row][col4 * 4] = p;
    }
    __syncthreads();

    const int cg  = tid & 7;
    const int pxg = tid >> 3;
    float acc[8][8];
#pragma unroll
    for (int j = 0; j < 8; ++j) {
        float bj = b[cg * 8 + j];
#pragma unroll
        for (int p = 0; p < 8; ++p) acc[j][p] = bj;
    }
#pragma unroll 8
    for (int c = 0; c < 64; ++c) {
        uint4 xv = *(const uint4*)&xt[c][pxg * 8];
        float xs[8] = {bflo(xv.x), bfhi(xv.x), bflo(xv.y), bfhi(xv.y),
                       bflo(xv.z), bfhi(xv.z), bflo(xv.w), bfhi(xv.w)};
        float2 w01 = *(const float2*)&wt[c][cg * 8 + 0];
        float2 w23 = *(const float2*)&wt[c][cg * 8 + 2];
        float2 w45 = *(const float2*)&wt[c][cg * 8 + 4];
        float2 w67 = *(const float2*)&wt[c][cg * 8 + 6];
        float wv[8] = {w01.x, w01.y, w23.x, w23.y, w45.x, w45.y, w67.x, w67.y};
#pragma unroll
        for (int j = 0; j < 8; ++j)
#pragma unroll
            for (int p = 0; p < 8; ++p) acc[j][p] = fmaf(wv[j], xs[p], acc[j][p]);
    }
#pragma unroll
    for (int p = 0; p < 8; ++p) {
        uint4 o;
        o.x = pack2(acc[0][p], acc[1][p]);
        o.y = pack2(acc[2][p], acc[3][p]);
        o.z = pack2(acc[4][p], acc[5][p]);
        o.w = pack2(acc[6][p], acc[7][p]);
        *(uint4*)(k1 + ((size_t)pg0 + pxg * 8 + p) * 64 + cg * 8) = o;
    }
}

// ---- Kernel W: repack enc weights  ew[kk][cm][3][3] -> ewt[tap][cm][kk] ----
__global__ __launch_bounds__(256) void kW_repack(const float* __restrict__ ew,
                                                 float* __restrict__ ewt) {
    int i = blockIdx.x * 256 + threadIdx.x;
    if (i < 25 * 64 * 9) {
        int tap = i % 9;
        int r   = i / 9;
        int cm  = r % 64;
        int kk  = r / 64;
        ewt[(tap * 64 + cm) * 25 + kk] = ew[i];
    }
}

// -------- Kernel B: 3x3 s2 enc conv (64->25) + softmax -> ksm fp32 ----------
__global__ __launch_bounds__(256) void kB_enc(const u16* __restrict__ k1,
                                              const float* __restrict__ ewt,
                                              const float* __restrict__ eb,
                                              float* __restrict__ ksm) {
    __shared__ float red[4][64][29];
    const int tid  = threadIdx.x;
    const int lane = tid & 63;
    const int quarter = __builtin_amdgcn_readfirstlane(tid >> 6);
    const int pix = blockIdx.x * 64 + lane;
    const int n   = pix >> 14;
    const int hd  = (pix >> 7) & 127;      // wave-uniform
    const int wd  = pix & 127;
    const int cm0 = quarter * 16;

    float acc[25];
#pragma unroll
    for (int kk = 0; kk < 25; ++kk) acc[kk] = 0.f;

    const u16* kbase = k1 + (size_t)n * HWP * 64;

    for (int dy = 0; dy < 3; ++dy) {
        int y = 2 * hd + dy - 1;
        if (y < 0 || y >= H) continue;
        for (int dx = 0; dx < 3; ++dx) {
            int xx = 2 * wd + dx - 1;
            bool ok = (xx >= 0);
            int xc = max(xx, 0);
            const int tap = dy * 3 + dx;
            const u16* kp = kbase + ((size_t)y * W + xc) * 64 + cm0;
            uint4 a = *(const uint4*)kp;
            uint4 bq = *(const uint4*)(kp + 8);
            float v[16] = {bflo(a.x),  bfhi(a.x),  bflo(a.y),  bfhi(a.y),
                           bflo(a.z),  bfhi(a.z),  bflo(a.w),  bfhi(a.w),
                           bflo(bq.x), bfhi(bq.x), bflo(bq.y), bfhi(bq.y),
                           bflo(bq.z), bfhi(bq.z), bflo(bq.w), bfhi(bq.w)};
            if (!ok) {
#pragma unroll
                for (int i = 0; i < 16; ++i) v[i] = 0.f;
            }
            const float* wp = ewt + (tap * 64 + cm0) * 25;
#pragma unroll
            for (int i = 0; i < 16; ++i)
#pragma unroll
                for (int kk = 0; kk < 25; ++kk)
                    acc[kk] = fmaf(v[i], wp[i * 25 + kk], acc[kk]);
        }
    }
#pragma unroll
    for (int kk = 0; kk < 25; ++kk) red[quarter][lane][kk] = acc[kk];
    __syncthreads();

    if (tid < 64) {
        float lg[25];
        float m = -1e30f;
#pragma unroll
        for (int kk = 0; kk < 25; ++kk) {
            float s = red[0][tid][kk] + red[1][tid][kk] + red[2][tid][kk]
                    + red[3][tid][kk] + eb[kk];
            lg[kk] = s;
            m = fmaxf(m, s);
        }
        float ssum = 0.f;
#pragma unroll
        for (int kk = 0; kk < 25; ++kk) { lg[kk] = __expf(lg[kk] - m); ssum += lg[kk]; }
        float inv = 1.f / ssum;
        float* ob = ksm + (size_t)n * KK * HDWD + hd * Wd + wd;
#pragma unroll
        for (int kk = 0; kk < 25; ++kk) ob[(size_t)kk * HDWD] = lg[kk] * inv;
    }
}

// ---- Kernel C: weighted reassembly -> out2 (N,256,Hd,Wd) bf16 --------------
// grid(2048): b -> cchunk(8ch)=b&7, hdt(4 hd)= (b>>3)&31, q=(b>>8)&3, n=b>>10.
// Thread = 2 wd outputs -> kw[25] float2 = 50 VGPR (no spill).
// Staging: flat float4 slots, lane-contiguous writes (conflict-free);
// 6 rows x 68 slots, halo slots zeroed. Data col w at float offset 4+w.
__global__ __launch_bounds__(256) void kC_reassemble(const float* __restrict__ x,
                                                     const float* __restrict__ ksm,
                                                     u16* __restrict__ out2) {
    __shared__ float xts[6 * 272];   // 6528 B
    const int tid = threadIdx.x;
    const int b   = blockIdx.x;
    const int cchunk = b & 7;
    const int hdt = (b >> 3) & 31;
    const int q   = (b >> 8) & 3;
    const int n   = b >> 10;
    const int hd0 = hdt * 4;
    const int wv   = tid >> 6;        // wave 0..3 -> hd row
    const int lane = tid & 63;
    const int hd  = hd0 + wv;
    const int wd0 = lane * 2;
    const int w0  = ((wv & 1) << 7) + wd0;   // image col of first output
    const int lr0 = wv >> 1;                 // staging row of h-2
    const int y0  = q * 64 + (hd0 >> 1) - 2;
    const int c0  = cchunk * 8;

    // 25 softmax weights for (hd, wd0..wd0+1) in registers (float2)
    const float* kb = ksm + (size_t)n * KK * HDWD + hd * Wd + wd0;
    float2 kw[25];
#pragma unroll
    for (int kk = 0; kk < 25; ++kk) kw[kk] = *(const float2*)(kb + (size_t)kk * HDWD);

    // staging slots: thread owns slot tid and tid+256 (of 408)
    const int s0 = tid, s1 = tid + 256;
    const int r0s = s0 / 68, c40 = s0 - r0s * 68;
    const int r1s = s1 / 68, c41 = s1 - r1s * 68;
    const int ya = y0 + r0s, yb = y0 + r1s;
    const bool v0 = (c40 >= 1) & (c40 <= 64) & (ya >= 0) & (ya < H);
    const bool v1 = (s1 < 408) & (c41 >= 1) & (c41 <= 64) & (yb >= 0) & (yb < H);
    const float* xn = x + (size_t)n * C * HWP + (size_t)c0 * HWP;
    const float* g0 = xn + (size_t)ya * W + (c40 - 1) * 4;
    const float* g1 = xn + (size_t)yb * W + (c41 - 1) * 4;

    const float4 z = make_float4(0.f, 0.f, 0.f, 0.f);
    float4 p0 = v0 ? *(const float4*)g0 : z;
    float4 p1 = v1 ? *(const float4*)g1 : z;

    for (int ci = 0; ci < 8; ++ci) {
        __syncthreads();             // previous iteration's reads done
        *(float4*)&xts[4 * s0] = p0;
        if (s1 < 408) *(float4*)&xts[4 * s1] = p1;
        __syncthreads();

        if (ci < 7) {                // prefetch next channel
            p0 = v0 ? *(const float4*)(g0 + (size_t)(ci + 1) * HWP) : z;
            p1 = v1 ? *(const float4*)(g1 + (size_t)(ci + 1) * HWP) : z;
        }

        float a0 = 0.f, a1 = 0.f;
#pragma unroll
        for (int i = 0; i < 5; ++i) {
            // cols w0-2..w0+3 live at floats (w0+2)..(w0+7): three aligned float2
            const float* rr = &xts[(lr0 + i) * 272 + w0 + 2];
            float2 r0 = *(const float2*)(rr + 0);
            float2 r1 = *(const float2*)(rr + 2);
            float2 r2 = *(const float2*)(rr + 4);
            float f[6] = {r0.x, r0.y, r1.x, r1.y, r2.x, r2.y};
#pragma unroll
            for (int j = 0; j < 5; ++j) {
                const float2 kv = kw[i * 5 + j];
                a0 = fmaf(f[j + 0], kv.x, a0);
                a1 = fmaf(f[j + 1], kv.y, a1);
            }
        }
        const int c2 = 4 * (c0 + ci) + q;
        u16* op = out2 + ((size_t)(n * C2 + c2) * Hd + hd) * Wd + wd0;
        *(unsigned*)op = pack2(a0, a1);
    }
}

// ---- Kernel D: 1x1 out conv (256 -> 64) -> d_out fp32 ----------------------
__global__ __launch_bounds__(256) void kD_out(const u16* __restrict__ out2,
                                              const float* __restrict__ ow,
                                              const float* __restrict__ ob,
                                              float* __restrict__ out) {
    const int co0 = blockIdx.y * 4;
    const int pg  = blockIdx.x * 256 + threadIdx.x;
    const int n   = pg >> 12;
    const int hw  = (pg << 2) & (HDWD - 1);
    const u16* ib = out2 + (size_t)n * C2 * HDWD + hw;

    float acc[4][4];
#pragma unroll
    for (int j = 0; j < 4; ++j) {
        float bj = ob[co0 + j];
#pragma unroll
        for (int p = 0; p < 4; ++p) acc[j][p] = bj;
    }
    for (int c2 = 0; c2 < 256; c2 += 8) {
        uint2 u[8];
#pragma unroll
        for (int t = 0; t < 8; ++t)
            u[t] = *(const uint2*)(ib + (size_t)(c2 + t) * HDWD);
#pragma unroll
        for (int t = 0; t < 8; ++t) {
            float xs[4] = {bflo(u[t].x), bfhi(u[t].x), bflo(u[t].y), bfhi(u[t].y)};
#pragma unroll
            for (int j = 0; j < 4; ++j) {
                float wv = ow[(co0 + j) * 256 + c2 + t];
#pragma unroll
                for (int p = 0; p < 4; ++p) acc[j][p] = fmaf(wv, xs[p], acc[j][p]);
            }
        }
    }
#pragma unroll
    for (int j = 0; j < 4; ++j) {
        float* op = out + (size_t)(n * OC + co0 + j) * HDWD + hw;
        *(float4*)op = make_float4(acc[j][0], acc[j][1], acc[j][2], acc[j][3]);
    }
}

extern "C" void kernel_launch(void* const* d_in, const int* in_sizes, int n_in,
                              void* d_out, int out_size, void* d_ws, size_t ws_size,
                              hipStream_t stream) {
    const float* x  = (const float*)d_in[0];
    const float* dw = (const float*)d_in[1];
    const float* db = (const float*)d_in[2];
    const float* ew = (const float*)d_in[3];
    const float* eb = (const float*)d_in[4];
    const float* ow = (const float*)d_in[5];
    const float* ob = (const float*)d_in[6];
    float* out = (float*)d_out;

    char* ws = (char*)d_ws;
    u16*   k1   = (u16*)ws;                               // [n][px][cm] 16.8 MB
    float* ksm  = (float*)(ws + 16777216);                // 3.3 MB
    u16*   out2 = (u16*)(ws + 16777216 + 3276800);        // 16.8 MB
    float* ewt  = (float*)out2;   // kW writes, kB reads, kC clobbers after

    kA_down<<<dim3(512), dim3(256), 0, stream>>>(x, dw, db, k1);
    kW_repack<<<dim3(57), dim3(256), 0, stream>>>(ew, ewt);
    kB_enc<<<dim3(512), dim3(256), 0, stream>>>(k1, ewt, eb, ksm);
    kC_reassemble<<<dim3(2048), dim3(256), 0, stream>>>(x, ksm, out2);
    kD_out<<<dim3(32, 16), dim3(256), 0, stream>>>(out2, ow, ob, out);
}